// Round 1
// baseline (685.343 us; speedup 1.0000x reference)
//
#include <hip/hip_runtime.h>
#include <hip/hip_bf16.h>
#include <math.h>

#define NB 32
#define LA 512
#define LB 512
#define DD 768

typedef __bf16 bf16x4 __attribute__((ext_vector_type(4)));
typedef __bf16 bf16x8 __attribute__((ext_vector_type(8)));
typedef float f32x4 __attribute__((ext_vector_type(4)));

// padded LDS stride for reg-staged P tiles (bank-conflict-free, 16B rows)
#define LSTR 40

// async global->LDS, 16B per lane. LDS dest must be the WAVE-UNIFORM base;
// HW adds lane*16. Global addr is per-lane.
__device__ __forceinline__ void gload_lds16(const void* g, void* l) {
  __builtin_amdgcn_global_load_lds(
      (const __attribute__((address_space(1))) unsigned int*)g,
      (__attribute__((address_space(3))) unsigned int*)l, 16, 0, 0);
}

// ---------------------------------------------------------------------------
// Kernel 0: one-pass fp32 -> split-bf16 conversion (+ transposed high copies).
//   A[b][i][d] -> Ah,Al[b][i][d] (bf16), AhT[b][d][i] (bf16 high)
//   B[b][j][d] -> Bh,Bl[b][j][d],        BhT[b][d][j]
// Memory-bound: reads 100 MB, writes 150 MB (~40 us). Removes ALL fp32->bf16
// conversion VALU from the GEMM hot loops (paid once, not 4x per element).
// grid (DD/64, 512/64, 2*NB), 256 thr.
// ---------------------------------------------------------------------------
__global__ __launch_bounds__(256) void convert_kernel(
    const float* __restrict__ A, const float* __restrict__ B,
    __bf16* __restrict__ Ah, __bf16* __restrict__ Al,
    __bf16* __restrict__ Bh, __bf16* __restrict__ Bl,
    __bf16* __restrict__ AhT, __bf16* __restrict__ BhT) {
  const int zb = blockIdx.z;
  const int b = zb & (NB - 1);
  const bool isB = zb >= NB;
  const float* src = (isB ? B : A) + (size_t)b * 512 * DD;
  __bf16* H = (isB ? Bh : Ah) + (size_t)b * 512 * DD;
  __bf16* L = (isB ? Bl : Al) + (size_t)b * 512 * DD;
  __bf16* T = (isB ? BhT : AhT) + (size_t)b * DD * 512;
  const int d0 = blockIdx.x * 64, i0 = blockIdx.y * 64;
  __shared__ __bf16 Tt[64][72];  // [d-local][i-local], 144B rows (16B-aligned)
  const int t = threadIdx.x;
  const int c4 = t & 15, r = t >> 4;
#pragma unroll
  for (int p = 0; p < 4; ++p) {
    const int i = i0 + r + p * 16;
    const float4 v = *(const float4*)(src + (size_t)i * DD + d0 + c4 * 4);
    float vv[4] = {v.x, v.y, v.z, v.w};
    bf16x4 h, l;
#pragma unroll
    for (int q = 0; q < 4; ++q) {
      h[q] = (__bf16)vv[q];
      l[q] = (__bf16)(vv[q] - (float)h[q]);
    }
    *(bf16x4*)(H + (size_t)i * DD + d0 + c4 * 4) = h;
    *(bf16x4*)(L + (size_t)i * DD + d0 + c4 * 4) = l;
#pragma unroll
    for (int q = 0; q < 4; ++q) Tt[c4 * 4 + q][r + p * 16] = h[q];
  }
  __syncthreads();
  const int cc = t & 7, rr = t >> 3;
#pragma unroll
  for (int p = 0; p < 2; ++p) {
    const int d = d0 + rr + p * 32;
    *(bf16x8*)(T + (size_t)d * 512 + i0 + cc * 8) =
        *(bf16x8*)&Tt[rr + p * 32][cc * 8];
  }
}

// ---------------------------------------------------------------------------
// Kernel 1: E = A.B^T via 3-pass split-bf16 (hh + hl + lh), m97-style staging:
// global_load_lds dwordx4 of pre-converted bf16, zero conversion in loop.
// 128x128 tile, BK=32, 4 waves (2x2 of 64x64), 48 MFMA/K-step.
// ---------------------------------------------------------------------------
__global__ __launch_bounds__(256) void gemm_e_mfma(
    const __bf16* __restrict__ Ah, const __bf16* __restrict__ Al,
    const __bf16* __restrict__ Bh, const __bf16* __restrict__ Bl,
    float* __restrict__ E) {
  // linear [128][32] bf16 (64B rows) — REQUIRED contiguous for global_load_lds
  __shared__ __bf16 AhS[128][32], AlS[128][32], BhS[128][32], BlS[128][32];

  const int b = blockIdx.z;
  const int i0 = blockIdx.x * 128, j0 = blockIdx.y * 128;
  const __bf16* AhB = Ah + (size_t)b * LA * DD;
  const __bf16* AlB = Al + (size_t)b * LA * DD;
  const __bf16* BhB = Bh + (size_t)b * LB * DD;
  const __bf16* BlB = Bl + (size_t)b * LB * DD;
  float* Eb = E + (size_t)b * LA * LB;

  const int t = threadIdx.x;
  const int lane = t & 63, wave = t >> 6;
  const int wm = (wave >> 1) * 64, wn = (wave & 1) * 64;
  const int quad = lane >> 4, l16 = lane & 15;
  const int lrow = lane >> 2, lcol = (lane & 3) * 8;  // lane slot within chunk

  f32x4 acc[4][4] = {};

  for (int k0 = 0; k0 < DD; k0 += 32) {
    __syncthreads();  // all waves done reading previous tiles
#pragma unroll
    for (int n = 0; n < 2; ++n) {
      const int c = n * 4 + wave;        // 1KB chunk id (16 rows)
      const int row = c * 16 + lrow;
      const size_t gA = (size_t)(i0 + row) * DD + k0 + lcol;
      const size_t gB = (size_t)(j0 + row) * DD + k0 + lcol;
      gload_lds16(AhB + gA, (char*)&AhS[0][0] + c * 1024);
      gload_lds16(AlB + gA, (char*)&AlS[0][0] + c * 1024);
      gload_lds16(BhB + gB, (char*)&BhS[0][0] + c * 1024);
      gload_lds16(BlB + gB, (char*)&BlS[0][0] + c * 1024);
    }
    __syncthreads();  // drains vmcnt -> tiles ready

    bf16x8 fah[4], fal[4], fbh[4], fbl[4];
#pragma unroll
    for (int f = 0; f < 4; ++f) {
      fah[f] = *(bf16x8*)&AhS[wm + f * 16 + l16][quad * 8];
      fal[f] = *(bf16x8*)&AlS[wm + f * 16 + l16][quad * 8];
      fbh[f] = *(bf16x8*)&BhS[wn + f * 16 + l16][quad * 8];
      fbl[f] = *(bf16x8*)&BlS[wn + f * 16 + l16][quad * 8];
    }
#pragma unroll
    for (int fm = 0; fm < 4; ++fm)
#pragma unroll
      for (int fn = 0; fn < 4; ++fn) {
        acc[fm][fn] = __builtin_amdgcn_mfma_f32_16x16x32_bf16(fah[fm], fbh[fn], acc[fm][fn], 0, 0, 0);
        acc[fm][fn] = __builtin_amdgcn_mfma_f32_16x16x32_bf16(fah[fm], fbl[fn], acc[fm][fn], 0, 0, 0);
        acc[fm][fn] = __builtin_amdgcn_mfma_f32_16x16x32_bf16(fal[fm], fbh[fn], acc[fm][fn], 0, 0, 0);
      }
  }

#pragma unroll
  for (int fm = 0; fm < 4; ++fm)
#pragma unroll
    for (int r = 0; r < 4; ++r) {
      const int i = i0 + wm + fm * 16 + quad * 4 + r;
#pragma unroll
      for (int fn = 0; fn < 4; ++fn)
        Eb[(size_t)i * LB + j0 + wn + fn * 16 + l16] = acc[fm][fn][r];
    }
}

// ---------------------------------------------------------------------------
// Kernel 2: row softmax stats (axis=2) — one wave per row, unchanged.
// ---------------------------------------------------------------------------
__global__ __launch_bounds__(256) void row_stats_kernel(
    const float* __restrict__ E, float* __restrict__ rmax,
    float* __restrict__ rsum) {
  const int wave = threadIdx.x >> 6;
  const int lane = threadIdx.x & 63;
  const int row = blockIdx.x * 4 + wave;
  const float* Er = E + (size_t)row * LB;
  float vals[8];
  float m = -INFINITY;
#pragma unroll
  for (int c = 0; c < 8; ++c) {
    vals[c] = Er[lane + c * 64];
    m = fmaxf(m, vals[c]);
  }
#pragma unroll
  for (int off = 32; off > 0; off >>= 1) m = fmaxf(m, __shfl_xor(m, off));
  float s = 0.f;
#pragma unroll
  for (int c = 0; c < 8; ++c) s += __expf(vals[c] - m);
#pragma unroll
  for (int off = 32; off > 0; off >>= 1) s += __shfl_xor(s, off);
  if (lane == 0) { rmax[row] = m; rsum[row] = s; }
}

// ---------------------------------------------------------------------------
// Kernel 3a: column softmax partials — i-range split 8x for occupancy
// (64 blocks -> 512 blocks). grid (NB*LB/256, 8).
// ---------------------------------------------------------------------------
__global__ __launch_bounds__(256) void col_partial(
    const float* __restrict__ E, float* __restrict__ pcm,
    float* __restrict__ pcs) {
  const int c = blockIdx.x * 256 + threadIdx.x;  // global column id
  const int b = c >> 9, j = c & (LB - 1);
  const int i0 = blockIdx.y * 64;
  const float* Ep = E + ((size_t)b * LA + i0) * LB + j;
  float m = -INFINITY, s = 0.f;
#pragma unroll 4
  for (int i = 0; i < 64; ++i) {
    const float v = Ep[(size_t)i * LB];
    const float mn = fmaxf(m, v);
    s = s * __expf(m - mn) + __expf(v - mn);
    m = mn;
  }
  pcm[blockIdx.y * (NB * LB) + c] = m;
  pcs[blockIdx.y * (NB * LB) + c] = s;
}

// Kernel 3b: combine the 8 partials per column.
__global__ __launch_bounds__(256) void col_combine(
    const float* __restrict__ pcm, const float* __restrict__ pcs,
    float* __restrict__ cmax, float* __restrict__ csum) {
  const int c = blockIdx.x * 256 + threadIdx.x;
  float m = -INFINITY, s = 0.f;
#pragma unroll
  for (int p = 0; p < 8; ++p) {
    const float mp = pcm[p * (NB * LB) + c];
    const float sp = pcs[p * (NB * LB) + c];
    const float mn = fmaxf(m, mp);
    s = s * __expf(m - mn) + sp * __expf(mp - mn);
    m = mn;
  }
  cmax[c] = m;
  csum[c] = s;
}

// ---------------------------------------------------------------------------
// Kernel 4: a_tilde = softmax_row(E).B, fused m_a epilogue.
// P reg-staged from fp32 E (exp must happen here); B^T operand via
// global_load_lds from pre-transposed BhT[b][d][j].
// ---------------------------------------------------------------------------
__global__ __launch_bounds__(256) void gemm_at_mfma(
    const float* __restrict__ E, const __bf16* __restrict__ BhT,
    const float* __restrict__ A, const float* __restrict__ rmax,
    const float* __restrict__ rsum, float* __restrict__ Ma) {
  __shared__ __bf16 Ps[128][LSTR];  // [i][j], padded
  __shared__ __bf16 Bs[128][32];    // [d][j], linear for global_load_lds
  __shared__ float rm_s[128], rs_s[128];

  const int b = blockIdx.z;
  const int i0 = blockIdx.x * 128, d0 = blockIdx.y * 128;
  const float* Eb = E + (size_t)b * LA * LB;
  const __bf16* Tb = BhT + (size_t)b * DD * LB;
  const float* Ab = A + (size_t)b * LA * DD;

  const int t = threadIdx.x;
  const int lane = t & 63, wave = t >> 6;
  const int wm = (wave >> 1) * 64, wn = (wave & 1) * 64;
  const int quad = lane >> 4, l16 = lane & 15;
  const int sr = t >> 3, sc = t & 7;
  const int lrow = lane >> 2, lcol = (lane & 3) * 8;

  if (t < 128) {
    rm_s[t] = rmax[b * LA + i0 + t];
    rs_s[t] = 1.f / rsum[b * LA + i0 + t];
  }
  __syncthreads();

  f32x4 acc[4][4] = {};

  for (int k0 = 0; k0 < LB; k0 += 32) {
    float4 ev[4];
#pragma unroll
    for (int p = 0; p < 4; ++p)
      ev[p] = *(const float4*)(Eb + (size_t)(i0 + sr + p * 32) * LB + k0 + sc * 4);
    __syncthreads();  // prev-iter LDS reads done
#pragma unroll
    for (int n = 0; n < 2; ++n) {
      const int c = n * 4 + wave;
      gload_lds16(Tb + (size_t)(d0 + c * 16 + lrow) * LB + k0 + lcol,
                  (char*)&Bs[0][0] + c * 1024);
    }
#pragma unroll
    for (int p = 0; p < 4; ++p) {  // overlaps gload latency
      const int m = sr + p * 32;
      const float rmv = rm_s[m], rsv = rs_s[m];
      float v[4] = {ev[p].x, ev[p].y, ev[p].z, ev[p].w};
      bf16x4 pb;
#pragma unroll
      for (int q = 0; q < 4; ++q) pb[q] = (__bf16)(__expf(v[q] - rmv) * rsv);
      *(bf16x4*)&Ps[m][sc * 4] = pb;
    }
    __syncthreads();

    bf16x8 fa[4], fb[4];
#pragma unroll
    for (int f = 0; f < 4; ++f) {
      fa[f] = *(bf16x8*)&Ps[wm + f * 16 + l16][quad * 8];
      fb[f] = *(bf16x8*)&Bs[wn + f * 16 + l16][quad * 8];
    }
#pragma unroll
    for (int fm = 0; fm < 4; ++fm)
#pragma unroll
      for (int fn = 0; fn < 4; ++fn)
        acc[fm][fn] = __builtin_amdgcn_mfma_f32_16x16x32_bf16(fa[fm], fb[fn], acc[fm][fn], 0, 0, 0);
  }

#pragma unroll
  for (int fm = 0; fm < 4; ++fm)
#pragma unroll
    for (int r = 0; r < 4; ++r) {
      const int i = i0 + wm + fm * 16 + quad * 4 + r;
      float* base = Ma + ((size_t)b * LA + i) * (4 * DD);
#pragma unroll
      for (int fn = 0; fn < 4; ++fn) {
        const int d = d0 + wn + fn * 16 + l16;
        const float av = Ab[(size_t)i * DD + d];
        const float at = acc[fm][fn][r];
        base[d] = av;
        base[DD + d] = at;
        base[2 * DD + d] = av - at;
        base[3 * DD + d] = av * at;
      }
    }
}

// ---------------------------------------------------------------------------
// Kernel 5: b_tilde = softmax_col(E)^T.A, fused m_b epilogue.
// P2 reg-staged transposed from E; A^T operand via global_load_lds from AhT.
// ---------------------------------------------------------------------------
__global__ __launch_bounds__(256) void gemm_bt_mfma(
    const float* __restrict__ E, const __bf16* __restrict__ AhT,
    const float* __restrict__ Bm, const float* __restrict__ cmax,
    const float* __restrict__ csum, float* __restrict__ Mb) {
  __shared__ __bf16 Ps[128][LSTR];  // [j][i], padded
  __shared__ __bf16 As[128][32];    // [d][i], linear
  __shared__ float cm_s[128], cs_s[128];

  const int b = blockIdx.z;
  const int j0 = blockIdx.x * 128, d0 = blockIdx.y * 128;
  const float* Eb = E + (size_t)b * LA * LB;
  const __bf16* Tb = AhT + (size_t)b * DD * LA;
  const float* Bb = Bm + (size_t)b * LB * DD;

  const int t = threadIdx.x;
  const int lane = t & 63, wave = t >> 6;
  const int wm = (wave >> 1) * 64, wn = (wave & 1) * 64;
  const int quad = lane >> 4, l16 = lane & 15;
  const int ir = t >> 3, ic = t & 7;
  const int lrow = lane >> 2, lcol = (lane & 3) * 8;

  if (t < 128) {
    cm_s[t] = cmax[b * LB + j0 + t];
    cs_s[t] = 1.f / csum[b * LB + j0 + t];
  }
  __syncthreads();

  f32x4 acc[4][4] = {};

  for (int k0 = 0; k0 < LA; k0 += 32) {
    float4 ev[4];
#pragma unroll
    for (int p = 0; p < 4; ++p)
      ev[p] = *(const float4*)(Eb + (size_t)(k0 + ir) * LB + j0 + p * 32 + ic * 4);
    __syncthreads();
#pragma unroll
    for (int n = 0; n < 2; ++n) {
      const int c = n * 4 + wave;
      gload_lds16(Tb + (size_t)(d0 + c * 16 + lrow) * LA + k0 + lcol,
                  (char*)&As[0][0] + c * 1024);
    }
#pragma unroll
    for (int p = 0; p < 4; ++p) {
      const float4 cm4 = *(const float4*)&cm_s[p * 32 + ic * 4];
      const float4 cs4 = *(const float4*)&cs_s[p * 32 + ic * 4];
      float v[4] = {ev[p].x, ev[p].y, ev[p].z, ev[p].w};
      float cmv[4] = {cm4.x, cm4.y, cm4.z, cm4.w};
      float csv[4] = {cs4.x, cs4.y, cs4.z, cs4.w};
#pragma unroll
      for (int q = 0; q < 4; ++q)
        Ps[p * 32 + ic * 4 + q][ir] = (__bf16)(__expf(v[q] - cmv[q]) * csv[q]);
    }
    __syncthreads();

    bf16x8 fa[4], fb[4];
#pragma unroll
    for (int f = 0; f < 4; ++f) {
      fa[f] = *(bf16x8*)&Ps[wm + f * 16 + l16][quad * 8];
      fb[f] = *(bf16x8*)&As[wn + f * 16 + l16][quad * 8];
    }
#pragma unroll
    for (int fm = 0; fm < 4; ++fm)
#pragma unroll
      for (int fn = 0; fn < 4; ++fn)
        acc[fm][fn] = __builtin_amdgcn_mfma_f32_16x16x32_bf16(fa[fm], fb[fn], acc[fm][fn], 0, 0, 0);
  }

#pragma unroll
  for (int fm = 0; fm < 4; ++fm)
#pragma unroll
    for (int r = 0; r < 4; ++r) {
      const int j = j0 + wm + fm * 16 + quad * 4 + r;
      float* base = Mb + ((size_t)b * LB + j) * (4 * DD);
#pragma unroll
      for (int fn = 0; fn < 4; ++fn) {
        const int d = d0 + wn + fn * 16 + l16;
        const float bvv = Bb[(size_t)j * DD + d];
        const float bt = acc[fm][fn][r];
        base[d] = bvv;
        base[DD + d] = bt;
        base[2 * DD + d] = bvv - bt;
        base[3 * DD + d] = bvv * bt;
      }
    }
}

// ---------------------------------------------------------------------------
extern "C" void kernel_launch(void* const* d_in, const int* in_sizes, int n_in,
                              void* d_out, int out_size, void* d_ws,
                              size_t ws_size, hipStream_t stream) {
  const float* a = (const float*)d_in[0];
  const float* bb = (const float*)d_in[1];
  float* out = (float*)d_out;
  float* Ma = out;
  float* Mb = out + (size_t)NB * LA * 4 * DD;

  char* p = (char*)d_ws;
  float* E = (float*)p;      p += (size_t)NB * LA * LB * 4;   // 33.55 MB
  float* rmax = (float*)p;   p += (size_t)NB * LA * 4;
  float* rsum = (float*)p;   p += (size_t)NB * LA * 4;
  float* cmax = (float*)p;   p += (size_t)NB * LB * 4;
  float* csum = (float*)p;   p += (size_t)NB * LB * 4;
  float* pcm = (float*)p;    p += (size_t)8 * NB * LB * 4;
  float* pcs = (float*)p;    p += (size_t)8 * NB * LB * 4;
  __bf16* Ah = (__bf16*)p;   p += (size_t)NB * LA * DD * 2;   // 25.2 MB each
  __bf16* Al = (__bf16*)p;   p += (size_t)NB * LA * DD * 2;
  __bf16* Bh = (__bf16*)p;   p += (size_t)NB * LB * DD * 2;
  __bf16* Bl = (__bf16*)p;   p += (size_t)NB * LB * DD * 2;
  __bf16* AhT = (__bf16*)p;  p += (size_t)NB * DD * LA * 2;
  __bf16* BhT = (__bf16*)p;  p += (size_t)NB * DD * LB * 2;

  convert_kernel<<<dim3(DD / 64, 512 / 64, 2 * NB), 256, 0, stream>>>(
      a, bb, Ah, Al, Bh, Bl, AhT, BhT);
  gemm_e_mfma<<<dim3(LA / 128, LB / 128, NB), 256, 0, stream>>>(Ah, Al, Bh, Bl, E);
  row_stats_kernel<<<dim3(NB * LA / 4), 256, 0, stream>>>(E, rmax, rsum);
  col_partial<<<dim3(NB * LB / 256, 8), 256, 0, stream>>>(E, pcm, pcs);
  col_combine<<<dim3(NB * LB / 256), 256, 0, stream>>>(pcm, pcs, cmax, csum);
  gemm_at_mfma<<<dim3(LA / 128, DD / 128, NB), 256, 0, stream>>>(E, BhT, a, rmax,
                                                                 rsum, Ma);
  gemm_bt_mfma<<<dim3(LB / 128, DD / 128, NB), 256, 0, stream>>>(E, AhT, bb, cmax,
                                                                 csum, Mb);
}

// Round 2
// 684.232 us; speedup vs baseline: 1.0016x; 1.0016x over previous
//
#include <hip/hip_runtime.h>
#include <hip/hip_bf16.h>
#include <math.h>

#define NB 32
#define LA 512
#define LB 512
#define DD 768

typedef __bf16 bf16x4 __attribute__((ext_vector_type(4)));
typedef __bf16 bf16x8 __attribute__((ext_vector_type(8)));
typedef float f32x4 __attribute__((ext_vector_type(4)));

// padded LDS stride for reg-staged P tiles (bank-conflict-free, 16B rows)
#define LSTR 40

// async global->LDS, 16B per lane. LDS dest must be the WAVE-UNIFORM base;
// HW adds lane*16. Global addr is per-lane.
__device__ __forceinline__ void gload_lds16(const void* g, void* l) {
  __builtin_amdgcn_global_load_lds(
      (const __attribute__((address_space(1))) unsigned int*)g,
      (__attribute__((address_space(3))) unsigned int*)l, 16, 0, 0);
}

// ---------------------------------------------------------------------------
// Kernel 0: one-pass fp32 -> split-bf16 conversion (+ transposed high copies).
// ---------------------------------------------------------------------------
__global__ __launch_bounds__(256) void convert_kernel(
    const float* __restrict__ A, const float* __restrict__ B,
    __bf16* __restrict__ Ah, __bf16* __restrict__ Al,
    __bf16* __restrict__ Bh, __bf16* __restrict__ Bl,
    __bf16* __restrict__ AhT, __bf16* __restrict__ BhT) {
  const int zb = blockIdx.z;
  const int b = zb & (NB - 1);
  const bool isB = zb >= NB;
  const float* src = (isB ? B : A) + (size_t)b * 512 * DD;
  __bf16* H = (isB ? Bh : Ah) + (size_t)b * 512 * DD;
  __bf16* L = (isB ? Bl : Al) + (size_t)b * 512 * DD;
  __bf16* T = (isB ? BhT : AhT) + (size_t)b * DD * 512;
  const int d0 = blockIdx.x * 64, i0 = blockIdx.y * 64;
  __shared__ __bf16 Tt[64][72];
  const int t = threadIdx.x;
  const int c4 = t & 15, r = t >> 4;
#pragma unroll
  for (int p = 0; p < 4; ++p) {
    const int i = i0 + r + p * 16;
    const float4 v = *(const float4*)(src + (size_t)i * DD + d0 + c4 * 4);
    float vv[4] = {v.x, v.y, v.z, v.w};
    bf16x4 h, l;
#pragma unroll
    for (int q = 0; q < 4; ++q) {
      h[q] = (__bf16)vv[q];
      l[q] = (__bf16)(vv[q] - (float)h[q]);
    }
    *(bf16x4*)(H + (size_t)i * DD + d0 + c4 * 4) = h;
    *(bf16x4*)(L + (size_t)i * DD + d0 + c4 * 4) = l;
#pragma unroll
    for (int q = 0; q < 4; ++q) Tt[c4 * 4 + q][r + p * 16] = h[q];
  }
  __syncthreads();
  const int cc = t & 7, rr = t >> 3;
#pragma unroll
  for (int p = 0; p < 2; ++p) {
    const int d = d0 + rr + p * 32;
    *(bf16x8*)(T + (size_t)d * 512 + i0 + cc * 8) =
        *(bf16x8*)&Tt[rr + p * 32][cc * 8];
  }
}

// ---------------------------------------------------------------------------
// Kernel 1: E = A.B^T, 3-pass split-bf16, 2-PHASE double-buffered prefetch:
// stage tile k+1 (global_load_lds) BEFORE ds_read+MFMA of tile k; one
// barrier per K-step (drain lands after ~48 MFMAs have hidden the latency).
// 1D grid 512, bijective XCD swizzle.
// ---------------------------------------------------------------------------
__global__ __launch_bounds__(256) void gemm_e_mfma(
    const __bf16* __restrict__ Ah, const __bf16* __restrict__ Al,
    const __bf16* __restrict__ Bh, const __bf16* __restrict__ Bl,
    float* __restrict__ E) {
  // [buf][arr: 0=Ah 1=Al 2=Bh 3=Bl][row][k] : 64 KB, linear for gload_lds
  __shared__ __bf16 S[2][4][128][32];

  // XCD swizzle: nwg=512 (%8==0) -> 64 consecutive wg per XCD = 4 batches
  const int id = blockIdx.x;
  const int wg = (id & 7) * 64 + (id >> 3);
  const int b = wg >> 4, tl = wg & 15;
  const int i0 = (tl & 3) * 128, j0 = (tl >> 2) * 128;

  const __bf16* AhB = Ah + (size_t)b * LA * DD;
  const __bf16* AlB = Al + (size_t)b * LA * DD;
  const __bf16* BhB = Bh + (size_t)b * LB * DD;
  const __bf16* BlB = Bl + (size_t)b * LB * DD;
  float* Eb = E + (size_t)b * LA * LB;

  const int t = threadIdx.x;
  const int lane = t & 63, wave = t >> 6;
  const int wm = (wave >> 1) * 64, wn = (wave & 1) * 64;
  const int quad = lane >> 4, l16 = lane & 15;
  const int lrow = lane >> 2, lcol = (lane & 3) * 8;

  auto stage = [&](int buf, int k0) {
#pragma unroll
    for (int n = 0; n < 2; ++n) {
      const int c = n * 4 + wave;  // 1KB chunk (16 rows)
      const int row = c * 16 + lrow;
      const size_t gA = (size_t)(i0 + row) * DD + k0 + lcol;
      const size_t gB = (size_t)(j0 + row) * DD + k0 + lcol;
      char* base = (char*)&S[buf][0][0][0];
      gload_lds16(AhB + gA, base + c * 1024);
      gload_lds16(AlB + gA, base + 8192 + c * 1024);
      gload_lds16(BhB + gB, base + 16384 + c * 1024);
      gload_lds16(BlB + gB, base + 24576 + c * 1024);
    }
  };

  f32x4 acc[4][4] = {};

  stage(0, 0);
  __syncthreads();  // vmcnt(0) drain: buf0 ready
  int cur = 0;
  for (int k0 = 0; k0 < DD; k0 += 32) {
    if (k0 + 32 < DD) stage(cur ^ 1, k0 + 32);  // prefetch BEFORE compute

    bf16x8 fah[4], fal[4], fbh[4], fbl[4];
#pragma unroll
    for (int f = 0; f < 4; ++f) {
      fah[f] = *(bf16x8*)&S[cur][0][wm + f * 16 + l16][quad * 8];
      fal[f] = *(bf16x8*)&S[cur][1][wm + f * 16 + l16][quad * 8];
      fbh[f] = *(bf16x8*)&S[cur][2][wn + f * 16 + l16][quad * 8];
      fbl[f] = *(bf16x8*)&S[cur][3][wn + f * 16 + l16][quad * 8];
    }
#pragma unroll
    for (int fm = 0; fm < 4; ++fm)
#pragma unroll
      for (int fn = 0; fn < 4; ++fn) {
        acc[fm][fn] = __builtin_amdgcn_mfma_f32_16x16x32_bf16(fah[fm], fbh[fn], acc[fm][fn], 0, 0, 0);
        acc[fm][fn] = __builtin_amdgcn_mfma_f32_16x16x32_bf16(fah[fm], fbl[fn], acc[fm][fn], 0, 0, 0);
        acc[fm][fn] = __builtin_amdgcn_mfma_f32_16x16x32_bf16(fal[fm], fbh[fn], acc[fm][fn], 0, 0, 0);
      }
    __syncthreads();  // next buf ready; all waves done reading cur
    cur ^= 1;
  }

#pragma unroll
  for (int fm = 0; fm < 4; ++fm)
#pragma unroll
    for (int r = 0; r < 4; ++r) {
      const int i = i0 + wm + fm * 16 + quad * 4 + r;
#pragma unroll
      for (int fn = 0; fn < 4; ++fn)
        Eb[(size_t)i * LB + j0 + wn + fn * 16 + l16] = acc[fm][fn][r];
    }
}

// ---------------------------------------------------------------------------
// Kernel 2: row softmax stats (axis=2)
// ---------------------------------------------------------------------------
__global__ __launch_bounds__(256) void row_stats_kernel(
    const float* __restrict__ E, float* __restrict__ rmax,
    float* __restrict__ rsum) {
  const int wave = threadIdx.x >> 6;
  const int lane = threadIdx.x & 63;
  const int row = blockIdx.x * 4 + wave;
  const float* Er = E + (size_t)row * LB;
  float vals[8];
  float m = -INFINITY;
#pragma unroll
  for (int c = 0; c < 8; ++c) {
    vals[c] = Er[lane + c * 64];
    m = fmaxf(m, vals[c]);
  }
#pragma unroll
  for (int off = 32; off > 0; off >>= 1) m = fmaxf(m, __shfl_xor(m, off));
  float s = 0.f;
#pragma unroll
  for (int c = 0; c < 8; ++c) s += __expf(vals[c] - m);
#pragma unroll
  for (int off = 32; off > 0; off >>= 1) s += __shfl_xor(s, off);
  if (lane == 0) { rmax[row] = m; rsum[row] = s; }
}

// ---------------------------------------------------------------------------
// Kernel 3a/3b: column softmax partials + combine
// ---------------------------------------------------------------------------
__global__ __launch_bounds__(256) void col_partial(
    const float* __restrict__ E, float* __restrict__ pcm,
    float* __restrict__ pcs) {
  const int c = blockIdx.x * 256 + threadIdx.x;
  const int b = c >> 9, j = c & (LB - 1);
  const int i0 = blockIdx.y * 64;
  const float* Ep = E + ((size_t)b * LA + i0) * LB + j;
  float m = -INFINITY, s = 0.f;
#pragma unroll 4
  for (int i = 0; i < 64; ++i) {
    const float v = Ep[(size_t)i * LB];
    const float mn = fmaxf(m, v);
    s = s * __expf(m - mn) + __expf(v - mn);
    m = mn;
  }
  pcm[blockIdx.y * (NB * LB) + c] = m;
  pcs[blockIdx.y * (NB * LB) + c] = s;
}

__global__ __launch_bounds__(256) void col_combine(
    const float* __restrict__ pcm, const float* __restrict__ pcs,
    float* __restrict__ cmax, float* __restrict__ csum) {
  const int c = blockIdx.x * 256 + threadIdx.x;
  float m = -INFINITY, s = 0.f;
#pragma unroll
  for (int p = 0; p < 8; ++p) {
    const float mp = pcm[p * (NB * LB) + c];
    const float sp = pcs[p * (NB * LB) + c];
    const float mn = fmaxf(m, mp);
    s = s * __expf(m - mn) + sp * __expf(mp - mn);
    m = mn;
  }
  cmax[c] = m;
  csum[c] = s;
}

// ---------------------------------------------------------------------------
// Kernel 4: a_tilde = softmax_row(E).B, 2-phase dbuf, fused m_a epilogue.
// 1D grid 768, XCD swizzle, d0 fastest within XCD chunk (E L2-reuse).
// ---------------------------------------------------------------------------
__global__ __launch_bounds__(256) void gemm_at_mfma(
    const float* __restrict__ E, const __bf16* __restrict__ BhT,
    const float* __restrict__ A, const float* __restrict__ rmax,
    const float* __restrict__ rsum, float* __restrict__ Ma) {
  __shared__ __bf16 Ps[2][128][LSTR];  // [i][j], padded (reg-staged)
  __shared__ __bf16 Bs[2][128][32];    // [d][j], linear (gload_lds)
  __shared__ float rm_s[128], rs_s[128];

  const int id = blockIdx.x;           // nwg=768, q=96
  const int wg = (id & 7) * 96 + (id >> 3);
  const int b = wg / 24, r24 = wg % 24;
  const int i0 = (r24 / 6) * 128, d0 = (r24 % 6) * 128;

  const float* Eb = E + (size_t)b * LA * LB;
  const __bf16* Tb = BhT + (size_t)b * DD * LB;
  const float* Ab = A + (size_t)b * LA * DD;

  const int t = threadIdx.x;
  const int lane = t & 63, wave = t >> 6;
  const int wm = (wave >> 1) * 64, wn = (wave & 1) * 64;
  const int quad = lane >> 4, l16 = lane & 15;
  const int sr = t >> 3, sc = t & 7;
  const int lrow = lane >> 2, lcol = (lane & 3) * 8;

  if (t < 128) {
    rm_s[t] = rmax[b * LA + i0 + t];
    rs_s[t] = 1.f / rsum[b * LA + i0 + t];
  }
  __syncthreads();

  auto loadE = [&](int k0, float4* ev) {
#pragma unroll
    for (int p = 0; p < 4; ++p)
      ev[p] = *(const float4*)(Eb + (size_t)(i0 + sr + p * 32) * LB + k0 + sc * 4);
  };
  auto stageB = [&](int buf, int k0) {
#pragma unroll
    for (int n = 0; n < 2; ++n) {
      const int c = n * 4 + wave;
      gload_lds16(Tb + (size_t)(d0 + c * 16 + lrow) * LB + k0 + lcol,
                  (char*)&Bs[buf][0][0] + c * 1024);
    }
  };
  auto writeP = [&](int buf, const float4* ev) {
#pragma unroll
    for (int p = 0; p < 4; ++p) {
      const int m = sr + p * 32;
      const float rmv = rm_s[m], rsv = rs_s[m];
      float v[4] = {ev[p].x, ev[p].y, ev[p].z, ev[p].w};
      bf16x4 pb;
#pragma unroll
      for (int q = 0; q < 4; ++q) pb[q] = (__bf16)(__expf(v[q] - rmv) * rsv);
      *(bf16x4*)&Ps[buf][m][sc * 4] = pb;
    }
  };

  f32x4 acc[4][4] = {};

  float4 ev[4];
  loadE(0, ev);
  stageB(0, 0);
  writeP(0, ev);
  __syncthreads();
  int cur = 0;
  for (int k0 = 0; k0 < LB; k0 += 32) {
    const bool nxt = (k0 + 32 < LB);
    float4 evn[4];
    if (nxt) { loadE(k0 + 32, evn); stageB(cur ^ 1, k0 + 32); }

    bf16x8 fa[4], fb[4];
#pragma unroll
    for (int f = 0; f < 4; ++f) {
      fa[f] = *(bf16x8*)&Ps[cur][wm + f * 16 + l16][quad * 8];
      fb[f] = *(bf16x8*)&Bs[cur][wn + f * 16 + l16][quad * 8];
    }
#pragma unroll
    for (int fm = 0; fm < 4; ++fm)
#pragma unroll
      for (int fn = 0; fn < 4; ++fn)
        acc[fm][fn] = __builtin_amdgcn_mfma_f32_16x16x32_bf16(fa[fm], fb[fn], acc[fm][fn], 0, 0, 0);

    if (nxt) writeP(cur ^ 1, evn);  // exp VALU overlaps MFMA pipe
    __syncthreads();
    cur ^= 1;
  }

#pragma unroll
  for (int fm = 0; fm < 4; ++fm)
#pragma unroll
    for (int r = 0; r < 4; ++r) {
      const int i = i0 + wm + fm * 16 + quad * 4 + r;
      float* base = Ma + ((size_t)b * LA + i) * (4 * DD);
#pragma unroll
      for (int fn = 0; fn < 4; ++fn) {
        const int d = d0 + wn + fn * 16 + l16;
        const float av = Ab[(size_t)i * DD + d];
        const float at = acc[fm][fn][r];
        base[d] = av;
        base[DD + d] = at;
        base[2 * DD + d] = av - at;
        base[3 * DD + d] = av * at;
      }
    }
}

// ---------------------------------------------------------------------------
// Kernel 5: b_tilde = softmax_col(E)^T.A, 2-phase dbuf, fused m_b epilogue.
// ---------------------------------------------------------------------------
__global__ __launch_bounds__(256) void gemm_bt_mfma(
    const float* __restrict__ E, const __bf16* __restrict__ AhT,
    const float* __restrict__ Bm, const float* __restrict__ cmax,
    const float* __restrict__ csum, float* __restrict__ Mb) {
  __shared__ __bf16 Ps[2][128][LSTR];  // [j][i], padded (reg-staged, transposed)
  __shared__ __bf16 As[2][128][32];    // [d][i], linear (gload_lds)
  __shared__ float cm_s[128], cs_s[128];

  const int id = blockIdx.x;           // nwg=768, q=96
  const int wg = (id & 7) * 96 + (id >> 3);
  const int b = wg / 24, r24 = wg % 24;
  const int j0 = (r24 / 6) * 128, d0 = (r24 % 6) * 128;

  const float* Eb = E + (size_t)b * LA * LB;
  const __bf16* Tb = AhT + (size_t)b * DD * LA;
  const float* Bb = Bm + (size_t)b * LB * DD;

  const int t = threadIdx.x;
  const int lane = t & 63, wave = t >> 6;
  const int wm = (wave >> 1) * 64, wn = (wave & 1) * 64;
  const int quad = lane >> 4, l16 = lane & 15;
  const int ir = t >> 3, ic = t & 7;
  const int lrow = lane >> 2, lcol = (lane & 3) * 8;

  if (t < 128) {
    cm_s[t] = cmax[b * LB + j0 + t];
    cs_s[t] = 1.f / csum[b * LB + j0 + t];
  }
  __syncthreads();

  auto loadE = [&](int k0, float4* ev) {
#pragma unroll
    for (int p = 0; p < 4; ++p)
      ev[p] = *(const float4*)(Eb + (size_t)(k0 + ir) * LB + j0 + p * 32 + ic * 4);
  };
  auto stageA = [&](int buf, int k0) {
#pragma unroll
    for (int n = 0; n < 2; ++n) {
      const int c = n * 4 + wave;
      gload_lds16(Tb + (size_t)(d0 + c * 16 + lrow) * LA + k0 + lcol,
                  (char*)&As[buf][0][0] + c * 1024);
    }
  };
  auto writeP = [&](int buf, const float4* ev) {
#pragma unroll
    for (int p = 0; p < 4; ++p) {
      const float4 cm4 = *(const float4*)&cm_s[p * 32 + ic * 4];
      const float4 cs4 = *(const float4*)&cs_s[p * 32 + ic * 4];
      float v[4] = {ev[p].x, ev[p].y, ev[p].z, ev[p].w};
      float cmv[4] = {cm4.x, cm4.y, cm4.z, cm4.w};
      float csv[4] = {cs4.x, cs4.y, cs4.z, cs4.w};
#pragma unroll
      for (int q = 0; q < 4; ++q)
        Ps[buf][p * 32 + ic * 4 + q][ir] = (__bf16)(__expf(v[q] - cmv[q]) * csv[q]);
    }
  };

  f32x4 acc[4][4] = {};

  float4 ev[4];
  loadE(0, ev);
  stageA(0, 0);
  writeP(0, ev);
  __syncthreads();
  int cur = 0;
  for (int k0 = 0; k0 < LA; k0 += 32) {
    const bool nxt = (k0 + 32 < LA);
    float4 evn[4];
    if (nxt) { loadE(k0 + 32, evn); stageA(cur ^ 1, k0 + 32); }

    bf16x8 fa[4], fb[4];
#pragma unroll
    for (int f = 0; f < 4; ++f) {
      fa[f] = *(bf16x8*)&Ps[cur][wm + f * 16 + l16][quad * 8];
      fb[f] = *(bf16x8*)&As[cur][wn + f * 16 + l16][quad * 8];
    }
#pragma unroll
    for (int fm = 0; fm < 4; ++fm)
#pragma unroll
      for (int fn = 0; fn < 4; ++fn)
        acc[fm][fn] = __builtin_amdgcn_mfma_f32_16x16x32_bf16(fa[fm], fb[fn], acc[fm][fn], 0, 0, 0);

    if (nxt) writeP(cur ^ 1, evn);
    __syncthreads();
    cur ^= 1;
  }

#pragma unroll
  for (int fm = 0; fm < 4; ++fm)
#pragma unroll
    for (int r = 0; r < 4; ++r) {
      const int j = j0 + wm + fm * 16 + quad * 4 + r;
      float* base = Mb + ((size_t)b * LB + j) * (4 * DD);
#pragma unroll
      for (int fn = 0; fn < 4; ++fn) {
        const int d = d0 + wn + fn * 16 + l16;
        const float bvv = Bb[(size_t)j * DD + d];
        const float bt = acc[fm][fn][r];
        base[d] = bvv;
        base[DD + d] = bt;
        base[2 * DD + d] = bvv - bt;
        base[3 * DD + d] = bvv * bt;
      }
    }
}

// ---------------------------------------------------------------------------
extern "C" void kernel_launch(void* const* d_in, const int* in_sizes, int n_in,
                              void* d_out, int out_size, void* d_ws,
                              size_t ws_size, hipStream_t stream) {
  const float* a = (const float*)d_in[0];
  const float* bb = (const float*)d_in[1];
  float* out = (float*)d_out;
  float* Ma = out;
  float* Mb = out + (size_t)NB * LA * 4 * DD;

  char* p = (char*)d_ws;
  float* E = (float*)p;      p += (size_t)NB * LA * LB * 4;
  float* rmax = (float*)p;   p += (size_t)NB * LA * 4;
  float* rsum = (float*)p;   p += (size_t)NB * LA * 4;
  float* cmax = (float*)p;   p += (size_t)NB * LB * 4;
  float* csum = (float*)p;   p += (size_t)NB * LB * 4;
  float* pcm = (float*)p;    p += (size_t)8 * NB * LB * 4;
  float* pcs = (float*)p;    p += (size_t)8 * NB * LB * 4;
  __bf16* Ah = (__bf16*)p;   p += (size_t)NB * LA * DD * 2;
  __bf16* Al = (__bf16*)p;   p += (size_t)NB * LA * DD * 2;
  __bf16* Bh = (__bf16*)p;   p += (size_t)NB * LB * DD * 2;
  __bf16* Bl = (__bf16*)p;   p += (size_t)NB * LB * DD * 2;
  __bf16* AhT = (__bf16*)p;  p += (size_t)NB * DD * LA * 2;
  __bf16* BhT = (__bf16*)p;  p += (size_t)NB * DD * LB * 2;

  convert_kernel<<<dim3(DD / 64, 512 / 64, 2 * NB), 256, 0, stream>>>(
      a, bb, Ah, Al, Bh, Bl, AhT, BhT);
  gemm_e_mfma<<<dim3(512), 256, 0, stream>>>(Ah, Al, Bh, Bl, E);
  row_stats_kernel<<<dim3(NB * LA / 4), 256, 0, stream>>>(E, rmax, rsum);
  col_partial<<<dim3(NB * LB / 256, 8), 256, 0, stream>>>(E, pcm, pcs);
  col_combine<<<dim3(NB * LB / 256), 256, 0, stream>>>(pcm, pcs, cmax, csum);
  gemm_at_mfma<<<dim3(768), 256, 0, stream>>>(E, BhT, a, rmax, rsum, Ma);
  gemm_bt_mfma<<<dim3(768), 256, 0, stream>>>(E, AhT, bb, cmax, csum, Mb);
}

// Round 3
// 672.710 us; speedup vs baseline: 1.0188x; 1.0171x over previous
//
#include <hip/hip_runtime.h>
#include <hip/hip_bf16.h>
#include <math.h>

#define NB 32
#define LA 512
#define LB 512
#define DD 768

typedef __bf16 bf16x4 __attribute__((ext_vector_type(4)));
typedef __bf16 bf16x8 __attribute__((ext_vector_type(8)));
typedef float f32x4 __attribute__((ext_vector_type(4)));

// async global->LDS, 16B per lane. LDS dest must be the WAVE-UNIFORM base;
// HW adds lane*16. Global addr is per-lane.
__device__ __forceinline__ void gload_lds16(const void* g, void* l) {
  __builtin_amdgcn_global_load_lds(
      (const __attribute__((address_space(1))) unsigned int*)g,
      (__attribute__((address_space(3))) unsigned int*)l, 16, 0, 0);
}

// ---------------------------------------------------------------------------
// Kernel 0: one-pass fp32 -> split-bf16 conversion (+ transposed high copies).
// ---------------------------------------------------------------------------
__global__ __launch_bounds__(256) void convert_kernel(
    const float* __restrict__ A, const float* __restrict__ B,
    __bf16* __restrict__ Ah, __bf16* __restrict__ Al,
    __bf16* __restrict__ Bh, __bf16* __restrict__ Bl,
    __bf16* __restrict__ AhT, __bf16* __restrict__ BhT) {
  const int zb = blockIdx.z;
  const int b = zb & (NB - 1);
  const bool isB = zb >= NB;
  const float* src = (isB ? B : A) + (size_t)b * 512 * DD;
  __bf16* H = (isB ? Bh : Ah) + (size_t)b * 512 * DD;
  __bf16* L = (isB ? Bl : Al) + (size_t)b * 512 * DD;
  __bf16* T = (isB ? BhT : AhT) + (size_t)b * DD * 512;
  const int d0 = blockIdx.x * 64, i0 = blockIdx.y * 64;
  __shared__ __bf16 Tt[64][72];
  const int t = threadIdx.x;
  const int c4 = t & 15, r = t >> 4;
#pragma unroll
  for (int p = 0; p < 4; ++p) {
    const int i = i0 + r + p * 16;
    const float4 v = *(const float4*)(src + (size_t)i * DD + d0 + c4 * 4);
    float vv[4] = {v.x, v.y, v.z, v.w};
    bf16x4 h, l;
#pragma unroll
    for (int q = 0; q < 4; ++q) {
      h[q] = (__bf16)vv[q];
      l[q] = (__bf16)(vv[q] - (float)h[q]);
    }
    *(bf16x4*)(H + (size_t)i * DD + d0 + c4 * 4) = h;
    *(bf16x4*)(L + (size_t)i * DD + d0 + c4 * 4) = l;
#pragma unroll
    for (int q = 0; q < 4; ++q) Tt[c4 * 4 + q][r + p * 16] = h[q];
  }
  __syncthreads();
  const int cc = t & 7, rr = t >> 3;
#pragma unroll
  for (int p = 0; p < 2; ++p) {
    const int d = d0 + rr + p * 32;
    *(bf16x8*)(T + (size_t)d * 512 + i0 + cc * 8) =
        *(bf16x8*)&Tt[rr + p * 32][cc * 8];
  }
}

// ---------------------------------------------------------------------------
// Kernel 1: E = A.B^T, 3-pass split-bf16, 2-phase dbuf prefetch, XCD swizzle.
// ---------------------------------------------------------------------------
__global__ __launch_bounds__(256) void gemm_e_mfma(
    const __bf16* __restrict__ Ah, const __bf16* __restrict__ Al,
    const __bf16* __restrict__ Bh, const __bf16* __restrict__ Bl,
    float* __restrict__ E) {
  __shared__ __bf16 S[2][4][128][32];  // 64 KB, linear for gload_lds

  const int id = blockIdx.x;
  const int wg = (id & 7) * 64 + (id >> 3);  // nwg=512, bijective
  const int b = wg >> 4, tl = wg & 15;
  const int i0 = (tl & 3) * 128, j0 = (tl >> 2) * 128;

  const __bf16* AhB = Ah + (size_t)b * LA * DD;
  const __bf16* AlB = Al + (size_t)b * LA * DD;
  const __bf16* BhB = Bh + (size_t)b * LB * DD;
  const __bf16* BlB = Bl + (size_t)b * LB * DD;
  float* Eb = E + (size_t)b * LA * LB;

  const int t = threadIdx.x;
  const int lane = t & 63, wave = t >> 6;
  const int wm = (wave >> 1) * 64, wn = (wave & 1) * 64;
  const int quad = lane >> 4, l16 = lane & 15;
  const int lrow = lane >> 2, lcol = (lane & 3) * 8;

  auto stage = [&](int buf, int k0) {
#pragma unroll
    for (int n = 0; n < 2; ++n) {
      const int c = n * 4 + wave;
      const int row = c * 16 + lrow;
      const size_t gA = (size_t)(i0 + row) * DD + k0 + lcol;
      const size_t gB = (size_t)(j0 + row) * DD + k0 + lcol;
      char* base = (char*)&S[buf][0][0][0];
      gload_lds16(AhB + gA, base + c * 1024);
      gload_lds16(AlB + gA, base + 8192 + c * 1024);
      gload_lds16(BhB + gB, base + 16384 + c * 1024);
      gload_lds16(BlB + gB, base + 24576 + c * 1024);
    }
  };

  f32x4 acc[4][4] = {};

  stage(0, 0);
  __syncthreads();
  int cur = 0;
  for (int k0 = 0; k0 < DD; k0 += 32) {
    if (k0 + 32 < DD) stage(cur ^ 1, k0 + 32);

    bf16x8 fah[4], fal[4], fbh[4], fbl[4];
#pragma unroll
    for (int f = 0; f < 4; ++f) {
      fah[f] = *(bf16x8*)&S[cur][0][wm + f * 16 + l16][quad * 8];
      fal[f] = *(bf16x8*)&S[cur][1][wm + f * 16 + l16][quad * 8];
      fbh[f] = *(bf16x8*)&S[cur][2][wn + f * 16 + l16][quad * 8];
      fbl[f] = *(bf16x8*)&S[cur][3][wn + f * 16 + l16][quad * 8];
    }
#pragma unroll
    for (int fm = 0; fm < 4; ++fm)
#pragma unroll
      for (int fn = 0; fn < 4; ++fn) {
        acc[fm][fn] = __builtin_amdgcn_mfma_f32_16x16x32_bf16(fah[fm], fbh[fn], acc[fm][fn], 0, 0, 0);
        acc[fm][fn] = __builtin_amdgcn_mfma_f32_16x16x32_bf16(fah[fm], fbl[fn], acc[fm][fn], 0, 0, 0);
        acc[fm][fn] = __builtin_amdgcn_mfma_f32_16x16x32_bf16(fal[fm], fbh[fn], acc[fm][fn], 0, 0, 0);
      }
    __syncthreads();
    cur ^= 1;
  }

#pragma unroll
  for (int fm = 0; fm < 4; ++fm)
#pragma unroll
    for (int r = 0; r < 4; ++r) {
      const int i = i0 + wm + fm * 16 + quad * 4 + r;
#pragma unroll
      for (int fn = 0; fn < 4; ++fn)
        Eb[(size_t)i * LB + j0 + wn + fn * 16 + l16] = acc[fm][fn][r];
    }
}

// ---------------------------------------------------------------------------
// Kernel 2: row softmax stats (axis=2)
// ---------------------------------------------------------------------------
__global__ __launch_bounds__(256) void row_stats_kernel(
    const float* __restrict__ E, float* __restrict__ rmax,
    float* __restrict__ rsum) {
  const int wave = threadIdx.x >> 6;
  const int lane = threadIdx.x & 63;
  const int row = blockIdx.x * 4 + wave;
  const float* Er = E + (size_t)row * LB;
  float vals[8];
  float m = -INFINITY;
#pragma unroll
  for (int c = 0; c < 8; ++c) {
    vals[c] = Er[lane + c * 64];
    m = fmaxf(m, vals[c]);
  }
#pragma unroll
  for (int off = 32; off > 0; off >>= 1) m = fmaxf(m, __shfl_xor(m, off));
  float s = 0.f;
#pragma unroll
  for (int c = 0; c < 8; ++c) s += __expf(vals[c] - m);
#pragma unroll
  for (int off = 32; off > 0; off >>= 1) s += __shfl_xor(s, off);
  if (lane == 0) { rmax[row] = m; rsum[row] = s; }
}

// ---------------------------------------------------------------------------
// Kernel 3a/3b: column softmax partials + combine
// ---------------------------------------------------------------------------
__global__ __launch_bounds__(256) void col_partial(
    const float* __restrict__ E, float* __restrict__ pcm,
    float* __restrict__ pcs) {
  const int c = blockIdx.x * 256 + threadIdx.x;
  const int b = c >> 9, j = c & (LB - 1);
  const int i0 = blockIdx.y * 64;
  const float* Ep = E + ((size_t)b * LA + i0) * LB + j;
  float m = -INFINITY, s = 0.f;
#pragma unroll 4
  for (int i = 0; i < 64; ++i) {
    const float v = Ep[(size_t)i * LB];
    const float mn = fmaxf(m, v);
    s = s * __expf(m - mn) + __expf(v - mn);
    m = mn;
  }
  pcm[blockIdx.y * (NB * LB) + c] = m;
  pcs[blockIdx.y * (NB * LB) + c] = s;
}

__global__ __launch_bounds__(256) void col_combine(
    const float* __restrict__ pcm, const float* __restrict__ pcs,
    float* __restrict__ cmax, float* __restrict__ csum) {
  const int c = blockIdx.x * 256 + threadIdx.x;
  float m = -INFINITY, s = 0.f;
#pragma unroll
  for (int p = 0; p < 8; ++p) {
    const float mp = pcm[p * (NB * LB) + c];
    const float sp = pcs[p * (NB * LB) + c];
    const float mn = fmaxf(m, mp);
    s = s * __expf(m - mn) + sp * __expf(mp - mn);
    m = mn;
  }
  cmax[c] = m;
  csum[c] = s;
}

// ---------------------------------------------------------------------------
// Kernel 3c: P materialization. Reads E once + stats; writes
//   Pa[b][i][j]  = exp(E-rm[i])*rsinv[i]   (bf16, row-major)
//   PbT[b][j][i] = exp(E-cm[j])*csinv[j]   (bf16, transposed via LDS)
// Removes ALL softmax VALU + fp32 E traffic from the downstream GEMMs.
// grid (4, 4, 32), 256 thr.
// ---------------------------------------------------------------------------
__global__ __launch_bounds__(256) void pconvert(
    const float* __restrict__ E, const float* __restrict__ rmax,
    const float* __restrict__ rsum, const float* __restrict__ cmax,
    const float* __restrict__ csum, __bf16* __restrict__ Pa,
    __bf16* __restrict__ PbT) {
  const int b = blockIdx.z;
  const int i0 = blockIdx.x * 128, j0 = blockIdx.y * 128;
  const float* Eb = E + (size_t)b * LA * LB;
  __shared__ __bf16 T[128][136];  // [j][i], rows 272B = 16B-aligned

  const int t = threadIdx.x;
  const int jr = t & 31, ir = t >> 5;  // 32 lanes x 4 floats = 128 cols; 8 rows
  const float4 cm4 = *(const float4*)&cmax[b * LB + j0 + jr * 4];
  const float4 cs4 = *(const float4*)&csum[b * LB + j0 + jr * 4];
  const float cmv[4] = {cm4.x, cm4.y, cm4.z, cm4.w};
  const float csv[4] = {1.f / cs4.x, 1.f / cs4.y, 1.f / cs4.z, 1.f / cs4.w};

#pragma unroll
  for (int p = 0; p < 16; ++p) {
    const int i = i0 + ir + p * 8;
    const float rm = rmax[b * LA + i];
    const float rs = 1.f / rsum[b * LA + i];
    const float4 v4 = *(const float4*)(Eb + (size_t)i * LB + j0 + jr * 4);
    const float v[4] = {v4.x, v4.y, v4.z, v4.w};
    bf16x4 pa;
#pragma unroll
    for (int q = 0; q < 4; ++q) {
      pa[q] = (__bf16)(__expf(v[q] - rm) * rs);
      T[jr * 4 + q][ir + p * 8] = (__bf16)(__expf(v[q] - cmv[q]) * csv[q]);
    }
    *(bf16x4*)(Pa + ((size_t)b * LA + i) * LB + j0 + jr * 4) = pa;
  }
  __syncthreads();
  const int jl = t >> 4, ch = t & 15;  // 16 rows/pass x 8 passes; 16 chunks of 16B
#pragma unroll
  for (int p = 0; p < 8; ++p) {
    const int j = jl + p * 16;
    *(bf16x8*)(PbT + ((size_t)b * LB + j0 + j) * LA + i0 + ch * 8) =
        *(bf16x8*)&T[j][ch * 8];
  }
}

// ---------------------------------------------------------------------------
// Kernel 4/5 (shared): out_tile = P(512xK=512) . T^T(768xK), pure bf16 GEMM,
// m97 structure: gload_lds both operands, 2-phase dbuf, 1 barrier/K-step,
// 32 KB LDS. Fused 4-way concat epilogue from fp32 source S.
//   at: P=Pa  (K=j), T=BhT, S=A,  out=Ma
//   bt: P=PbT (K=i), T=AhT, S=Bm, out=Mb
// 1D grid 768, XCD swizzle, d0 fastest (per-batch working set ~3MB fits L2).
// ---------------------------------------------------------------------------
__global__ __launch_bounds__(256) void gemm_pd(
    const __bf16* __restrict__ P, const __bf16* __restrict__ T,
    const float* __restrict__ S, float* __restrict__ Mout) {
  __shared__ __bf16 Ls[2][2][128][32];  // [buf][0=P,1=T][row][k], 32 KB

  const int id = blockIdx.x;            // nwg=768, q=96, bijective
  const int wg = (id & 7) * 96 + (id >> 3);
  const int b = wg / 24, r24 = wg % 24;
  const int m0 = (r24 / 6) * 128, d0 = (r24 % 6) * 128;

  const __bf16* Pb = P + (size_t)b * 512 * 512;
  const __bf16* Tb = T + (size_t)b * DD * 512;
  const float* Sb = S + (size_t)b * 512 * DD;

  const int t = threadIdx.x;
  const int lane = t & 63, wave = t >> 6;
  const int wm = (wave >> 1) * 64, wn = (wave & 1) * 64;
  const int quad = lane >> 4, l16 = lane & 15;
  const int lrow = lane >> 2, lcol = (lane & 3) * 8;

  auto stage = [&](int buf, int k0) {
#pragma unroll
    for (int n = 0; n < 2; ++n) {
      const int c = n * 4 + wave;
      const int row = c * 16 + lrow;
      char* base = (char*)&Ls[buf][0][0][0];
      gload_lds16(Pb + (size_t)(m0 + row) * 512 + k0 + lcol, base + c * 1024);
      gload_lds16(Tb + (size_t)(d0 + row) * 512 + k0 + lcol,
                  base + 8192 + c * 1024);
    }
  };

  f32x4 acc[4][4] = {};

  stage(0, 0);
  __syncthreads();
  int cur = 0;
  for (int k0 = 0; k0 < 512; k0 += 32) {
    if (k0 + 32 < 512) stage(cur ^ 1, k0 + 32);

    bf16x8 fa[4], fb[4];
#pragma unroll
    for (int f = 0; f < 4; ++f) {
      fa[f] = *(bf16x8*)&Ls[cur][0][wm + f * 16 + l16][quad * 8];
      fb[f] = *(bf16x8*)&Ls[cur][1][wn + f * 16 + l16][quad * 8];
    }
#pragma unroll
    for (int fm = 0; fm < 4; ++fm)
#pragma unroll
      for (int fn = 0; fn < 4; ++fn)
        acc[fm][fn] = __builtin_amdgcn_mfma_f32_16x16x32_bf16(fa[fm], fb[fn], acc[fm][fn], 0, 0, 0);
    __syncthreads();
    cur ^= 1;
  }

#pragma unroll
  for (int fm = 0; fm < 4; ++fm)
#pragma unroll
    for (int r = 0; r < 4; ++r) {
      const int m = m0 + wm + fm * 16 + quad * 4 + r;
      float* base = Mout + ((size_t)b * 512 + m) * (4 * DD);
      const float* srow = Sb + (size_t)m * DD;
#pragma unroll
      for (int fn = 0; fn < 4; ++fn) {
        const int d = d0 + wn + fn * 16 + l16;
        const float sv = srow[d];
        const float tv = acc[fm][fn][r];
        base[d] = sv;
        base[DD + d] = tv;
        base[2 * DD + d] = sv - tv;
        base[3 * DD + d] = sv * tv;
      }
    }
}

// ---------------------------------------------------------------------------
extern "C" void kernel_launch(void* const* d_in, const int* in_sizes, int n_in,
                              void* d_out, int out_size, void* d_ws,
                              size_t ws_size, hipStream_t stream) {
  const float* a = (const float*)d_in[0];
  const float* bb = (const float*)d_in[1];
  float* out = (float*)d_out;
  float* Ma = out;
  float* Mb = out + (size_t)NB * LA * 4 * DD;

  char* p = (char*)d_ws;
  float* E = (float*)p;      p += (size_t)NB * LA * LB * 4;
  float* rmax = (float*)p;   p += (size_t)NB * LA * 4;
  float* rsum = (float*)p;   p += (size_t)NB * LA * 4;
  float* cmax = (float*)p;   p += (size_t)NB * LB * 4;
  float* csum = (float*)p;   p += (size_t)NB * LB * 4;
  float* pcm = (float*)p;    p += (size_t)8 * NB * LB * 4;
  float* pcs = (float*)p;    p += (size_t)8 * NB * LB * 4;
  __bf16* Ah = (__bf16*)p;   p += (size_t)NB * LA * DD * 2;
  __bf16* Al = (__bf16*)p;   p += (size_t)NB * LA * DD * 2;
  __bf16* Bh = (__bf16*)p;   p += (size_t)NB * LB * DD * 2;
  __bf16* Bl = (__bf16*)p;   p += (size_t)NB * LB * DD * 2;
  __bf16* AhT = (__bf16*)p;  p += (size_t)NB * DD * LA * 2;
  __bf16* BhT = (__bf16*)p;  p += (size_t)NB * DD * LB * 2;
  __bf16* Pa = (__bf16*)p;   p += (size_t)NB * LA * LB * 2;
  __bf16* PbT = (__bf16*)p;  p += (size_t)NB * LB * LA * 2;

  convert_kernel<<<dim3(DD / 64, 512 / 64, 2 * NB), 256, 0, stream>>>(
      a, bb, Ah, Al, Bh, Bl, AhT, BhT);
  gemm_e_mfma<<<dim3(512), 256, 0, stream>>>(Ah, Al, Bh, Bl, E);
  row_stats_kernel<<<dim3(NB * LA / 4), 256, 0, stream>>>(E, rmax, rsum);
  col_partial<<<dim3(NB * LB / 256, 8), 256, 0, stream>>>(E, pcm, pcs);
  col_combine<<<dim3(NB * LB / 256), 256, 0, stream>>>(pcm, pcs, cmax, csum);
  pconvert<<<dim3(LA / 128, LB / 128, NB), 256, 0, stream>>>(E, rmax, rsum,
                                                             cmax, csum, Pa, PbT);
  gemm_pd<<<dim3(768), 256, 0, stream>>>(Pa, BhT, a, Ma);
  gemm_pd<<<dim3(768), 256, 0, stream>>>(PbT, AhT, bb, Mb);
}

// Round 4
// 658.861 us; speedup vs baseline: 1.0402x; 1.0210x over previous
//
#include <hip/hip_runtime.h>
#include <hip/hip_bf16.h>
#include <math.h>

#define NB 32
#define LA 512
#define LB 512
#define DD 768
#define SLABS 16  // column-stat slabs per batch (32 rows each)

typedef __bf16 bf16x4 __attribute__((ext_vector_type(4)));
typedef __bf16 bf16x8 __attribute__((ext_vector_type(8)));
typedef float f32x4 __attribute__((ext_vector_type(4)));

// async global->LDS, 16B per lane. LDS dest must be the WAVE-UNIFORM base;
// HW adds lane*16. Global addr is per-lane.
__device__ __forceinline__ void gload_lds16(const void* g, void* l) {
  __builtin_amdgcn_global_load_lds(
      (const __attribute__((address_space(1))) unsigned int*)g,
      (__attribute__((address_space(3))) unsigned int*)l, 16, 0, 0);
}

// ---------------------------------------------------------------------------
// Kernel 0: one-pass fp32 -> split-bf16 conversion (+ transposed high copies).
// ---------------------------------------------------------------------------
__global__ __launch_bounds__(256) void convert_kernel(
    const float* __restrict__ A, const float* __restrict__ B,
    __bf16* __restrict__ Ah, __bf16* __restrict__ Al,
    __bf16* __restrict__ Bh, __bf16* __restrict__ Bl,
    __bf16* __restrict__ AhT, __bf16* __restrict__ BhT) {
  const int zb = blockIdx.z;
  const int b = zb & (NB - 1);
  const bool isB = zb >= NB;
  const float* src = (isB ? B : A) + (size_t)b * 512 * DD;
  __bf16* H = (isB ? Bh : Ah) + (size_t)b * 512 * DD;
  __bf16* L = (isB ? Bl : Al) + (size_t)b * 512 * DD;
  __bf16* T = (isB ? BhT : AhT) + (size_t)b * DD * 512;
  const int d0 = blockIdx.x * 64, i0 = blockIdx.y * 64;
  __shared__ __bf16 Tt[64][72];
  const int t = threadIdx.x;
  const int c4 = t & 15, r = t >> 4;
#pragma unroll
  for (int p = 0; p < 4; ++p) {
    const int i = i0 + r + p * 16;
    const float4 v = *(const float4*)(src + (size_t)i * DD + d0 + c4 * 4);
    float vv[4] = {v.x, v.y, v.z, v.w};
    bf16x4 h, l;
#pragma unroll
    for (int q = 0; q < 4; ++q) {
      h[q] = (__bf16)vv[q];
      l[q] = (__bf16)(vv[q] - (float)h[q]);
    }
    *(bf16x4*)(H + (size_t)i * DD + d0 + c4 * 4) = h;
    *(bf16x4*)(L + (size_t)i * DD + d0 + c4 * 4) = l;
#pragma unroll
    for (int q = 0; q < 4; ++q) Tt[c4 * 4 + q][r + p * 16] = h[q];
  }
  __syncthreads();
  const int cc = t & 7, rr = t >> 3;
#pragma unroll
  for (int p = 0; p < 2; ++p) {
    const int d = d0 + rr + p * 32;
    *(bf16x8*)(T + (size_t)d * 512 + i0 + cc * 8) =
        *(bf16x8*)&Tt[rr + p * 32][cc * 8];
  }
}

// ---------------------------------------------------------------------------
// Kernel 1: E = A.B^T, 3-pass split-bf16, 2-phase dbuf prefetch, XCD swizzle.
// 64 KB LDS -> pin 2 blocks/CU (8 waves) via launch_bounds.
// ---------------------------------------------------------------------------
__global__ __launch_bounds__(256, 2) void gemm_e_mfma(
    const __bf16* __restrict__ Ah, const __bf16* __restrict__ Al,
    const __bf16* __restrict__ Bh, const __bf16* __restrict__ Bl,
    float* __restrict__ E) {
  __shared__ __bf16 S[2][4][128][32];  // 64 KB, linear for gload_lds

  const int id = blockIdx.x;
  const int wg = (id & 7) * 64 + (id >> 3);  // nwg=512, bijective
  const int b = wg >> 4, tl = wg & 15;
  const int i0 = (tl & 3) * 128, j0 = (tl >> 2) * 128;

  const __bf16* AhB = Ah + (size_t)b * LA * DD;
  const __bf16* AlB = Al + (size_t)b * LA * DD;
  const __bf16* BhB = Bh + (size_t)b * LB * DD;
  const __bf16* BlB = Bl + (size_t)b * LB * DD;
  float* Eb = E + (size_t)b * LA * LB;

  const int t = threadIdx.x;
  const int lane = t & 63, wave = t >> 6;
  const int wm = (wave >> 1) * 64, wn = (wave & 1) * 64;
  const int quad = lane >> 4, l16 = lane & 15;
  const int lrow = lane >> 2, lcol = (lane & 3) * 8;

  auto stage = [&](int buf, int k0) {
#pragma unroll
    for (int n = 0; n < 2; ++n) {
      const int c = n * 4 + wave;
      const int row = c * 16 + lrow;
      const size_t gA = (size_t)(i0 + row) * DD + k0 + lcol;
      const size_t gB = (size_t)(j0 + row) * DD + k0 + lcol;
      char* base = (char*)&S[buf][0][0][0];
      gload_lds16(AhB + gA, base + c * 1024);
      gload_lds16(AlB + gA, base + 8192 + c * 1024);
      gload_lds16(BhB + gB, base + 16384 + c * 1024);
      gload_lds16(BlB + gB, base + 24576 + c * 1024);
    }
  };

  f32x4 acc[4][4] = {};

  stage(0, 0);
  __syncthreads();
  int cur = 0;
  for (int k0 = 0; k0 < DD; k0 += 32) {
    if (k0 + 32 < DD) stage(cur ^ 1, k0 + 32);

    bf16x8 fah[4], fal[4], fbh[4], fbl[4];
#pragma unroll
    for (int f = 0; f < 4; ++f) {
      fah[f] = *(bf16x8*)&S[cur][0][wm + f * 16 + l16][quad * 8];
      fal[f] = *(bf16x8*)&S[cur][1][wm + f * 16 + l16][quad * 8];
      fbh[f] = *(bf16x8*)&S[cur][2][wn + f * 16 + l16][quad * 8];
      fbl[f] = *(bf16x8*)&S[cur][3][wn + f * 16 + l16][quad * 8];
    }
#pragma unroll
    for (int fm = 0; fm < 4; ++fm)
#pragma unroll
      for (int fn = 0; fn < 4; ++fn) {
        acc[fm][fn] = __builtin_amdgcn_mfma_f32_16x16x32_bf16(fah[fm], fbh[fn], acc[fm][fn], 0, 0, 0);
        acc[fm][fn] = __builtin_amdgcn_mfma_f32_16x16x32_bf16(fah[fm], fbl[fn], acc[fm][fn], 0, 0, 0);
        acc[fm][fn] = __builtin_amdgcn_mfma_f32_16x16x32_bf16(fal[fm], fbh[fn], acc[fm][fn], 0, 0, 0);
      }
    __syncthreads();
    cur ^= 1;
  }

#pragma unroll
  for (int fm = 0; fm < 4; ++fm)
#pragma unroll
    for (int r = 0; r < 4; ++r) {
      const int i = i0 + wm + fm * 16 + quad * 4 + r;
#pragma unroll
      for (int fn = 0; fn < 4; ++fn)
        Eb[(size_t)i * LB + j0 + wn + fn * 16 + l16] = acc[fm][fn][r];
    }
}

// ---------------------------------------------------------------------------
// Kernel 2: fused softmax stats. Per block: one 32-row slab of one batch.
//   - complete row stats (max + expsum over full 512-j rows), same reduction
//     order as the old row_stats_kernel.
//   - column partials over the slab's 32 rows (same as old col_partial with
//     finer i-split); slab is L2-hot for the second pass.
// grid NB*SLABS = 512 blocks.
// ---------------------------------------------------------------------------
__global__ __launch_bounds__(256) void estat_kernel(
    const float* __restrict__ E, float* __restrict__ rmax,
    float* __restrict__ rsum, float* __restrict__ pcm,
    float* __restrict__ pcs) {
  const int b = blockIdx.x >> 4, slab = blockIdx.x & 15;
  const int i0 = slab * 32;
  const float* Eb = E + (size_t)b * LA * LB;
  const int t = threadIdx.x;
  const int wave = t >> 6, lane = t & 63;

  // row stats: 8 rows per wave
  for (int rr = 0; rr < 8; ++rr) {
    const int i = i0 + wave * 8 + rr;
    const float* Er = Eb + (size_t)i * LB;
    float vals[8];
    float m = -INFINITY;
#pragma unroll
    for (int c = 0; c < 8; ++c) {
      vals[c] = Er[lane + c * 64];
      m = fmaxf(m, vals[c]);
    }
#pragma unroll
    for (int off = 32; off > 0; off >>= 1) m = fmaxf(m, __shfl_xor(m, off));
    float s = 0.f;
#pragma unroll
    for (int c = 0; c < 8; ++c) s += __expf(vals[c] - m);
#pragma unroll
    for (int off = 32; off > 0; off >>= 1) s += __shfl_xor(s, off);
    if (lane == 0) { rmax[b * LA + i] = m; rsum[b * LA + i] = s; }
  }

  // column partials over 32 rows; 2 columns per thread
#pragma unroll
  for (int h = 0; h < 2; ++h) {
    const int j = t + h * 256;
    const float* Ep = Eb + (size_t)i0 * LB + j;
    float m = -INFINITY, s = 0.f;
#pragma unroll 4
    for (int i = 0; i < 32; ++i) {
      const float v = Ep[(size_t)i * LB];
      const float mn = fmaxf(m, v);
      s = s * __expf(m - mn) + __expf(v - mn);
      m = mn;
    }
    pcm[slab * (NB * LB) + b * LB + j] = m;
    pcs[slab * (NB * LB) + b * LB + j] = s;
  }
}

// Kernel 2b: combine the SLABS partials per column.
__global__ __launch_bounds__(256) void col_combine(
    const float* __restrict__ pcm, const float* __restrict__ pcs,
    float* __restrict__ cmax, float* __restrict__ csum) {
  const int c = blockIdx.x * 256 + threadIdx.x;
  float m = -INFINITY, s = 0.f;
#pragma unroll
  for (int p = 0; p < SLABS; ++p) {
    const float mp = pcm[p * (NB * LB) + c];
    const float sp = pcs[p * (NB * LB) + c];
    const float mn = fmaxf(m, mp);
    s = s * __expf(m - mn) + sp * __expf(mp - mn);
    m = mn;
  }
  cmax[c] = m;
  csum[c] = s;
}

// ---------------------------------------------------------------------------
// Kernel 3: P materialization (unchanged from r3).
// ---------------------------------------------------------------------------
__global__ __launch_bounds__(256) void pconvert(
    const float* __restrict__ E, const float* __restrict__ rmax,
    const float* __restrict__ rsum, const float* __restrict__ cmax,
    const float* __restrict__ csum, __bf16* __restrict__ Pa,
    __bf16* __restrict__ PbT) {
  const int b = blockIdx.z;
  const int i0 = blockIdx.x * 128, j0 = blockIdx.y * 128;
  const float* Eb = E + (size_t)b * LA * LB;
  __shared__ __bf16 T[128][136];

  const int t = threadIdx.x;
  const int jr = t & 31, ir = t >> 5;
  const float4 cm4 = *(const float4*)&cmax[b * LB + j0 + jr * 4];
  const float4 cs4 = *(const float4*)&csum[b * LB + j0 + jr * 4];
  const float cmv[4] = {cm4.x, cm4.y, cm4.z, cm4.w};
  const float csv[4] = {1.f / cs4.x, 1.f / cs4.y, 1.f / cs4.z, 1.f / cs4.w};

#pragma unroll
  for (int p = 0; p < 16; ++p) {
    const int i = i0 + ir + p * 8;
    const float rm = rmax[b * LA + i];
    const float rs = 1.f / rsum[b * LA + i];
    const float4 v4 = *(const float4*)(Eb + (size_t)i * LB + j0 + jr * 4);
    const float v[4] = {v4.x, v4.y, v4.z, v4.w};
    bf16x4 pa;
#pragma unroll
    for (int q = 0; q < 4; ++q) {
      pa[q] = (__bf16)(__expf(v[q] - rm) * rs);
      T[jr * 4 + q][ir + p * 8] = (__bf16)(__expf(v[q] - cmv[q]) * csv[q]);
    }
    *(bf16x4*)(Pa + ((size_t)b * LA + i) * LB + j0 + jr * 4) = pa;
  }
  __syncthreads();
  const int jl = t >> 4, ch = t & 15;
#pragma unroll
  for (int p = 0; p < 8; ++p) {
    const int j = jl + p * 16;
    *(bf16x8*)(PbT + ((size_t)b * LB + j0 + j) * LA + i0 + ch * 8) =
        *(bf16x8*)&T[j][ch * 8];
  }
}

// ---------------------------------------------------------------------------
// Kernel 4: merged P.T^T GEMM for BOTH a_tilde and b_tilde halves.
// m97 structure, 32 KB LDS, pinned 3 blocks/CU. Fused 4-way concat epilogue.
// grid 1536 (first 768 = a-side, last 768 = b-side), XCD swizzle.
// ---------------------------------------------------------------------------
__global__ __launch_bounds__(256, 3) void gemm_pd(
    const __bf16* __restrict__ Pa, const __bf16* __restrict__ BhT,
    const float* __restrict__ A, float* __restrict__ Ma,
    const __bf16* __restrict__ PbT, const __bf16* __restrict__ AhT,
    const float* __restrict__ B, float* __restrict__ Mb) {
  __shared__ __bf16 Ls[2][2][128][32];  // [buf][0=P,1=T][row][k], 32 KB

  const int id = blockIdx.x;            // nwg=1536, q=192, bijective
  const int wg = (id & 7) * 192 + (id >> 3);
  const bool bside = wg >= 768;
  const int wg2 = bside ? wg - 768 : wg;
  const int b = wg2 / 24, r24 = wg2 % 24;
  const int m0 = (r24 / 6) * 128, d0 = (r24 % 6) * 128;

  const __bf16* P = bside ? PbT : Pa;
  const __bf16* T = bside ? AhT : BhT;
  const float* S = bside ? B : A;
  float* Mout = bside ? Mb : Ma;

  const __bf16* Pb = P + (size_t)b * 512 * 512;
  const __bf16* Tb = T + (size_t)b * DD * 512;
  const float* Sb = S + (size_t)b * 512 * DD;

  const int t = threadIdx.x;
  const int lane = t & 63, wave = t >> 6;
  const int wm = (wave >> 1) * 64, wn = (wave & 1) * 64;
  const int quad = lane >> 4, l16 = lane & 15;
  const int lrow = lane >> 2, lcol = (lane & 3) * 8;

  auto stage = [&](int buf, int k0) {
#pragma unroll
    for (int n = 0; n < 2; ++n) {
      const int c = n * 4 + wave;
      const int row = c * 16 + lrow;
      char* base = (char*)&Ls[buf][0][0][0];
      gload_lds16(Pb + (size_t)(m0 + row) * 512 + k0 + lcol, base + c * 1024);
      gload_lds16(Tb + (size_t)(d0 + row) * 512 + k0 + lcol,
                  base + 8192 + c * 1024);
    }
  };

  f32x4 acc[4][4] = {};

  stage(0, 0);
  __syncthreads();
  int cur = 0;
  for (int k0 = 0; k0 < 512; k0 += 32) {
    if (k0 + 32 < 512) stage(cur ^ 1, k0 + 32);

    bf16x8 fa[4], fb[4];
#pragma unroll
    for (int f = 0; f < 4; ++f) {
      fa[f] = *(bf16x8*)&Ls[cur][0][wm + f * 16 + l16][quad * 8];
      fb[f] = *(bf16x8*)&Ls[cur][1][wn + f * 16 + l16][quad * 8];
    }
#pragma unroll
    for (int fm = 0; fm < 4; ++fm)
#pragma unroll
      for (int fn = 0; fn < 4; ++fn)
        acc[fm][fn] = __builtin_amdgcn_mfma_f32_16x16x32_bf16(fa[fm], fb[fn], acc[fm][fn], 0, 0, 0);
    __syncthreads();
    cur ^= 1;
  }

#pragma unroll
  for (int fm = 0; fm < 4; ++fm)
#pragma unroll
    for (int r = 0; r < 4; ++r) {
      const int m = m0 + wm + fm * 16 + quad * 4 + r;
      float* base = Mout + ((size_t)b * 512 + m) * (4 * DD);
      const float* srow = Sb + (size_t)m * DD;
#pragma unroll
      for (int fn = 0; fn < 4; ++fn) {
        const int d = d0 + wn + fn * 16 + l16;
        const float sv = srow[d];
        const float tv = acc[fm][fn][r];
        base[d] = sv;
        base[DD + d] = tv;
        base[2 * DD + d] = sv - tv;
        base[3 * DD + d] = sv * tv;
      }
    }
}

// ---------------------------------------------------------------------------
extern "C" void kernel_launch(void* const* d_in, const int* in_sizes, int n_in,
                              void* d_out, int out_size, void* d_ws,
                              size_t ws_size, hipStream_t stream) {
  const float* a = (const float*)d_in[0];
  const float* bb = (const float*)d_in[1];
  float* out = (float*)d_out;
  float* Ma = out;
  float* Mb = out + (size_t)NB * LA * 4 * DD;

  char* p = (char*)d_ws;
  float* E = (float*)p;      p += (size_t)NB * LA * LB * 4;
  float* rmax = (float*)p;   p += (size_t)NB * LA * 4;
  float* rsum = (float*)p;   p += (size_t)NB * LA * 4;
  float* cmax = (float*)p;   p += (size_t)NB * LB * 4;
  float* csum = (float*)p;   p += (size_t)NB * LB * 4;
  float* pcm = (float*)p;    p += (size_t)SLABS * NB * LB * 4;
  float* pcs = (float*)p;    p += (size_t)SLABS * NB * LB * 4;
  __bf16* Ah = (__bf16*)p;   p += (size_t)NB * LA * DD * 2;
  __bf16* Al = (__bf16*)p;   p += (size_t)NB * LA * DD * 2;
  __bf16* Bh = (__bf16*)p;   p += (size_t)NB * LB * DD * 2;
  __bf16* Bl = (__bf16*)p;   p += (size_t)NB * LB * DD * 2;
  __bf16* AhT = (__bf16*)p;  p += (size_t)NB * DD * LA * 2;
  __bf16* BhT = (__bf16*)p;  p += (size_t)NB * DD * LB * 2;
  __bf16* Pa = (__bf16*)p;   p += (size_t)NB * LA * LB * 2;
  __bf16* PbT = (__bf16*)p;  p += (size_t)NB * LB * LA * 2;

  convert_kernel<<<dim3(DD / 64, 512 / 64, 2 * NB), 256, 0, stream>>>(
      a, bb, Ah, Al, Bh, Bl, AhT, BhT);
  gemm_e_mfma<<<dim3(512), 256, 0, stream>>>(Ah, Al, Bh, Bl, E);
  estat_kernel<<<dim3(NB * SLABS), 256, 0, stream>>>(E, rmax, rsum, pcm, pcs);
  col_combine<<<dim3(NB * LB / 256), 256, 0, stream>>>(pcm, pcs, cmax, csum);
  pconvert<<<dim3(LA / 128, LB / 128, NB), 256, 0, stream>>>(E, rmax, rsum,
                                                             cmax, csum, Pa, PbT);
  gemm_pd<<<dim3(1536), 256, 0, stream>>>(Pa, BhT, a, Ma, PbT, AhT, bb, Mb);
}